// Round 2
// baseline (2961.885 us; speedup 1.0000x reference)
//
#include <hip/hip_runtime.h>
#include <hip/hip_bf16.h>

#define IN_FEAT 256
#define HEADS 4
#define OUT_FEAT 64
#define NEG_SLOPE 0.2f

// ---------------- zero init (d_out is used as accumulator; ws holds denom) --
__global__ void zero_kernel(float* __restrict__ acc, float* __restrict__ denom,
                            int n_acc, int n_den) {
    int idx = blockIdx.x * blockDim.x + threadIdx.x;
    int stride = gridDim.x * blockDim.x;
    for (int i = idx; i < n_acc; i += stride) acc[i] = 0.f;
    for (int i = idx; i < n_den; i += stride) denom[i] = 0.f;
}

// ---------------- h = x @ W  (f32, 64x64 tile, BK=32) -----------------------
__global__ __launch_bounds__(256) void gemm_f32(const float* __restrict__ X,
                                                const float* __restrict__ W,
                                                float* __restrict__ H, int M) {
    __shared__ float sX[64][33];
    __shared__ float sW[32][65];
    const int bm = blockIdx.x * 64;
    const int bn = blockIdx.y * 64;
    const int tid = threadIdx.x;
    const int tx = tid & 15;   // 16 col groups of 4
    const int ty = tid >> 4;   // 16 row groups of 4
    float acc[4][4] = {};
    for (int k0 = 0; k0 < IN_FEAT; k0 += 32) {
        for (int i = tid; i < 64 * 32; i += 256) {
            int r = i >> 5, c = i & 31;
            sX[r][c] = (bm + r < M) ? X[(size_t)(bm + r) * IN_FEAT + k0 + c] : 0.f;
        }
        for (int i = tid; i < 32 * 64; i += 256) {
            int r = i >> 6, c = i & 63;
            sW[r][c] = W[(size_t)(k0 + r) * IN_FEAT + bn + c];
        }
        __syncthreads();
#pragma unroll
        for (int k = 0; k < 32; ++k) {
            float xv[4], wv[4];
#pragma unroll
            for (int i = 0; i < 4; ++i) xv[i] = sX[ty * 4 + i][k];
#pragma unroll
            for (int j = 0; j < 4; ++j) wv[j] = sW[k][tx * 4 + j];
#pragma unroll
            for (int i = 0; i < 4; ++i)
#pragma unroll
                for (int j = 0; j < 4; ++j) acc[i][j] += xv[i] * wv[j];
        }
        __syncthreads();
    }
#pragma unroll
    for (int i = 0; i < 4; ++i) {
        int r = bm + ty * 4 + i;
        if (r < M) {
#pragma unroll
            for (int j = 0; j < 4; ++j)
                H[(size_t)r * IN_FEAT + bn + tx * 4 + j] = acc[i][j];
        }
    }
}

// ---------------- per-node attention logits ---------------------------------
__global__ void node_logits(const float* __restrict__ H,
                            const float* __restrict__ att_src,
                            const float* __restrict__ att_dst,
                            float* __restrict__ asrc, float* __restrict__ adst,
                            int N) {
    int gtid = blockIdx.x * blockDim.x + threadIdx.x;
    int wave = gtid >> 6;
    int lane = threadIdx.x & 63;
    int nwaves = (gridDim.x * blockDim.x) >> 6;
    // att_src flat [4][64]; lane*4 = head*64 + (lane&15)*4
    const float4 as = *reinterpret_cast<const float4*>(&att_src[lane * 4]);
    const float4 ad = *reinterpret_cast<const float4*>(&att_dst[lane * 4]);
    for (int i = wave; i < N; i += nwaves) {
        const float4 hv = *reinterpret_cast<const float4*>(&H[(size_t)i * IN_FEAT + lane * 4]);
        float ps = hv.x * as.x + hv.y * as.y + hv.z * as.z + hv.w * as.w;
        float pd = hv.x * ad.x + hv.y * ad.y + hv.z * ad.z + hv.w * ad.w;
#pragma unroll
        for (int off = 1; off < 16; off <<= 1) {
            ps += __shfl_xor(ps, off, 64);
            pd += __shfl_xor(pd, off, 64);
        }
        if ((lane & 15) == 0) {
            int head = lane >> 4;
            asrc[i * HEADS + head] = ps;
            adst[i * HEADS + head] = pd;
        }
    }
}

// ---------------- edge scatter pass -----------------------------------------
__global__ void edge_kernel(const int* __restrict__ ei,
                            const float* __restrict__ H,
                            const float* __restrict__ asrc,
                            const float* __restrict__ adst,
                            float* __restrict__ acc, float* __restrict__ denom,
                            int E, int N) {
    int gtid = blockIdx.x * blockDim.x + threadIdx.x;
    int wave = gtid >> 6;
    int lane = threadIdx.x & 63;
    int nwaves = (gridDim.x * blockDim.x) >> 6;
    int head = lane >> 4;
    for (int e = wave; e < E; e += nwaves) {
        int s = ei[e];
        int d = ei[E + e];
        if ((unsigned)s >= (unsigned)N || (unsigned)d >= (unsigned)N) continue;
        float a = asrc[s * HEADS + head] + adst[d * HEADS + head];
        float lr = (a > 0.f) ? a : NEG_SLOPE * a;
        float w = __expf(lr);   // softmax is shift-invariant; logits are O(1)
        if ((lane & 15) == 0) unsafeAtomicAdd(&denom[d * HEADS + head], w);
        const float4 hv = *reinterpret_cast<const float4*>(&H[(size_t)s * IN_FEAT + lane * 4]);
        float* op = &acc[(size_t)d * IN_FEAT + lane * 4];
        unsafeAtomicAdd(op + 0, w * hv.x);
        unsafeAtomicAdd(op + 1, w * hv.y);
        unsafeAtomicAdd(op + 2, w * hv.z);
        unsafeAtomicAdd(op + 3, w * hv.w);
    }
}

// ---------------- finalize: self-loop + normalize + bias + relu -------------
__global__ void finalize(const float* __restrict__ H,
                         const float* __restrict__ asrc,
                         const float* __restrict__ adst,
                         const float* __restrict__ denom,
                         const float* __restrict__ bias,
                         float* __restrict__ out, int N) {
    int gtid = blockIdx.x * blockDim.x + threadIdx.x;
    int wave = gtid >> 6;
    int lane = threadIdx.x & 63;
    int nwaves = (gridDim.x * blockDim.x) >> 6;
    int head = lane >> 4;
    const float4 bv = *reinterpret_cast<const float4*>(&bias[lane * 4]);
    for (int i = wave; i < N; i += nwaves) {
        float a = asrc[i * HEADS + head] + adst[i * HEADS + head];
        float lr = (a > 0.f) ? a : NEG_SLOPE * a;
        float w = __expf(lr);                   // self-loop weight
        float dn = denom[i * HEADS + head] + w;
        const float4 hv = *reinterpret_cast<const float4*>(&H[(size_t)i * IN_FEAT + lane * 4]);
        float4 av = *reinterpret_cast<const float4*>(&out[(size_t)i * IN_FEAT + lane * 4]);
        float4 r;
        r.x = fmaxf((av.x + w * hv.x) / dn + bv.x, 0.f);
        r.y = fmaxf((av.y + w * hv.y) / dn + bv.y, 0.f);
        r.z = fmaxf((av.z + w * hv.z) / dn + bv.z, 0.f);
        r.w = fmaxf((av.w + w * hv.w) / dn + bv.w, 0.f);
        *reinterpret_cast<float4*>(&out[(size_t)i * IN_FEAT + lane * 4]) = r;
    }
}

extern "C" void kernel_launch(void* const* d_in, const int* in_sizes, int n_in,
                              void* d_out, int out_size, void* d_ws, size_t ws_size,
                              hipStream_t stream) {
    const float* x       = (const float*)d_in[0];
    const int*   ei      = (const int*)d_in[1];      // harness converts int64 -> int32
    const float* W       = (const float*)d_in[2];
    const float* att_src = (const float*)d_in[3];
    const float* att_dst = (const float*)d_in[4];
    const float* bias    = (const float*)d_in[5];
    float*       out     = (float*)d_out;

    const int N = in_sizes[0] / IN_FEAT;   // 50000
    const int E = in_sizes[1] / 2;         // 800000

    // workspace layout
    float* H     = (float*)d_ws;           // N*256
    float* asrc  = H + (size_t)N * IN_FEAT;
    float* adst  = asrc + (size_t)N * HEADS;
    float* denom = adst + (size_t)N * HEADS;

    zero_kernel<<<2048, 256, 0, stream>>>(out, denom, N * IN_FEAT, N * HEADS);
    {
        dim3 grid((N + 63) / 64, IN_FEAT / 64);
        gemm_f32<<<grid, 256, 0, stream>>>(x, W, H, N);
    }
    node_logits<<<1024, 256, 0, stream>>>(H, att_src, att_dst, asrc, adst, N);
    edge_kernel<<<2048, 256, 0, stream>>>(ei, H, asrc, adst, out, denom, E, N);
    finalize<<<1024, 256, 0, stream>>>(H, asrc, adst, denom, bias, out, N);
}

// Round 3
// 531.998 us; speedup vs baseline: 5.5675x; 5.5675x over previous
//
#include <hip/hip_runtime.h>
#include <hip/hip_bf16.h>

#define IN_FEAT 256
#define HEADS 4
#define OUT_FEAT 64
#define NEG_SLOPE 0.2f

// ---------------- zero counts ------------------------------------------------
__global__ void zero_counts(int* __restrict__ counts, int n) {
    int idx = blockIdx.x * blockDim.x + threadIdx.x;
    int stride = gridDim.x * blockDim.x;
    for (int i = idx; i < n; i += stride) counts[i] = 0;
}

// ---------------- histogram of destinations ---------------------------------
__global__ void hist_kernel(const int* __restrict__ ei, int* __restrict__ counts,
                            int E, int N) {
    int idx = blockIdx.x * blockDim.x + threadIdx.x;
    int stride = gridDim.x * blockDim.x;
    for (int e = idx; e < E; e += stride) {
        int d = ei[E + e];
        if ((unsigned)d < (unsigned)N) atomicAdd(&counts[d], 1);
    }
}

// ---------------- exclusive scan (single block, 1024 threads) ---------------
__global__ __launch_bounds__(1024) void scan_kernel(const int* __restrict__ counts,
                                                    int* __restrict__ offsets,
                                                    int* __restrict__ cursor, int N) {
    __shared__ int sdata[1024];
    const int t = threadIdx.x;
    const int chunk = (N + 1023) / 1024;
    const int begin = t * chunk;
    const int endi = min(begin + chunk, N);
    int sum = 0;
    for (int i = begin; i < endi; ++i) sum += counts[i];
    sdata[t] = sum;
    __syncthreads();
    for (int off = 1; off < 1024; off <<= 1) {
        int v = (t >= off) ? sdata[t - off] : 0;
        __syncthreads();
        sdata[t] += v;
        __syncthreads();
    }
    int run = (t == 0) ? 0 : sdata[t - 1];
    for (int i = begin; i < endi; ++i) {
        offsets[i] = run;
        cursor[i] = run;
        run += counts[i];
    }
}

// ---------------- scatter src ids into dst-sorted order ---------------------
__global__ void scatter_kernel(const int* __restrict__ ei, int* __restrict__ cursor,
                               int* __restrict__ sorted_src, int E, int N) {
    int idx = blockIdx.x * blockDim.x + threadIdx.x;
    int stride = gridDim.x * blockDim.x;
    for (int e = idx; e < E; e += stride) {
        int s = ei[e];
        int d = ei[E + e];
        if ((unsigned)s >= (unsigned)N || (unsigned)d >= (unsigned)N) continue;
        int pos = atomicAdd(&cursor[d], 1);
        sorted_src[pos] = s;
    }
}

// ---------------- h = x @ W  (f32, 64x64 tile, BK=32) -----------------------
__global__ __launch_bounds__(256) void gemm_f32(const float* __restrict__ X,
                                                const float* __restrict__ W,
                                                float* __restrict__ H, int M) {
    __shared__ float sX[64][33];
    __shared__ float sW[32][65];
    const int bm = blockIdx.x * 64;
    const int bn = blockIdx.y * 64;
    const int tid = threadIdx.x;
    const int tx = tid & 15;
    const int ty = tid >> 4;
    float acc[4][4] = {};
    for (int k0 = 0; k0 < IN_FEAT; k0 += 32) {
        for (int i = tid; i < 64 * 32; i += 256) {
            int r = i >> 5, c = i & 31;
            sX[r][c] = (bm + r < M) ? X[(size_t)(bm + r) * IN_FEAT + k0 + c] : 0.f;
        }
        for (int i = tid; i < 32 * 64; i += 256) {
            int r = i >> 6, c = i & 63;
            sW[r][c] = W[(size_t)(k0 + r) * IN_FEAT + bn + c];
        }
        __syncthreads();
#pragma unroll
        for (int k = 0; k < 32; ++k) {
            float xv[4], wv[4];
#pragma unroll
            for (int i = 0; i < 4; ++i) xv[i] = sX[ty * 4 + i][k];
#pragma unroll
            for (int j = 0; j < 4; ++j) wv[j] = sW[k][tx * 4 + j];
#pragma unroll
            for (int i = 0; i < 4; ++i)
#pragma unroll
                for (int j = 0; j < 4; ++j) acc[i][j] += xv[i] * wv[j];
        }
        __syncthreads();
    }
#pragma unroll
    for (int i = 0; i < 4; ++i) {
        int r = bm + ty * 4 + i;
        if (r < M) {
#pragma unroll
            for (int j = 0; j < 4; ++j)
                H[(size_t)r * IN_FEAT + bn + tx * 4 + j] = acc[i][j];
        }
    }
}

// ---------------- per-node attention logits ---------------------------------
__global__ void node_logits(const float* __restrict__ H,
                            const float* __restrict__ att_src,
                            const float* __restrict__ att_dst,
                            float* __restrict__ asrc, float* __restrict__ adst,
                            int N) {
    int gtid = blockIdx.x * blockDim.x + threadIdx.x;
    int wave = gtid >> 6;
    int lane = threadIdx.x & 63;
    int nwaves = (gridDim.x * blockDim.x) >> 6;
    const float4 as = *reinterpret_cast<const float4*>(&att_src[lane * 4]);
    const float4 ad = *reinterpret_cast<const float4*>(&att_dst[lane * 4]);
    for (int i = wave; i < N; i += nwaves) {
        const float4 hv = *reinterpret_cast<const float4*>(&H[(size_t)i * IN_FEAT + lane * 4]);
        float ps = hv.x * as.x + hv.y * as.y + hv.z * as.z + hv.w * as.w;
        float pd = hv.x * ad.x + hv.y * ad.y + hv.z * ad.z + hv.w * ad.w;
#pragma unroll
        for (int off = 1; off < 16; off <<= 1) {
            ps += __shfl_xor(ps, off, 64);
            pd += __shfl_xor(pd, off, 64);
        }
        if ((lane & 15) == 0) {
            int head = lane >> 4;
            asrc[i * HEADS + head] = ps;
            adst[i * HEADS + head] = pd;
        }
    }
}

// ---------------- gather aggregate: one wave per destination node -----------
__global__ __launch_bounds__(256) void aggregate(const float* __restrict__ H,
                                                 const float* __restrict__ asrc,
                                                 const float* __restrict__ adst,
                                                 const int* __restrict__ offsets,
                                                 const int* __restrict__ counts,
                                                 const int* __restrict__ sorted_src,
                                                 const float* __restrict__ bias,
                                                 float* __restrict__ out, int N) {
    int gtid = blockIdx.x * blockDim.x + threadIdx.x;
    int wave = gtid >> 6;
    int lane = threadIdx.x & 63;
    int nwaves = (gridDim.x * blockDim.x) >> 6;
    int head = lane >> 4;
    const float4 bv = *reinterpret_cast<const float4*>(&bias[lane * 4]);
    for (int d = wave; d < N; d += nwaves) {
        const float ad = adst[d * HEADS + head];
        // self-loop contribution
        float a = asrc[d * HEADS + head] + ad;
        float w = __expf((a > 0.f) ? a : NEG_SLOPE * a);
        const float4 hvd = *reinterpret_cast<const float4*>(&H[(size_t)d * IN_FEAT + lane * 4]);
        float4 acc = make_float4(w * hvd.x, w * hvd.y, w * hvd.z, w * hvd.w);
        float den = w;
        const int start = offsets[d];
        const int cnt = counts[d];
        int k = 0;
        for (; k + 1 < cnt; k += 2) {
            int s0 = sorted_src[start + k];
            int s1 = sorted_src[start + k + 1];
            float a0 = asrc[s0 * HEADS + head] + ad;
            float a1 = asrc[s1 * HEADS + head] + ad;
            const float4 h0 = *reinterpret_cast<const float4*>(&H[(size_t)s0 * IN_FEAT + lane * 4]);
            const float4 h1 = *reinterpret_cast<const float4*>(&H[(size_t)s1 * IN_FEAT + lane * 4]);
            float w0 = __expf((a0 > 0.f) ? a0 : NEG_SLOPE * a0);
            float w1 = __expf((a1 > 0.f) ? a1 : NEG_SLOPE * a1);
            acc.x += w0 * h0.x + w1 * h1.x;
            acc.y += w0 * h0.y + w1 * h1.y;
            acc.z += w0 * h0.z + w1 * h1.z;
            acc.w += w0 * h0.w + w1 * h1.w;
            den += w0 + w1;
        }
        if (k < cnt) {
            int s0 = sorted_src[start + k];
            float a0 = asrc[s0 * HEADS + head] + ad;
            const float4 h0 = *reinterpret_cast<const float4*>(&H[(size_t)s0 * IN_FEAT + lane * 4]);
            float w0 = __expf((a0 > 0.f) ? a0 : NEG_SLOPE * a0);
            acc.x += w0 * h0.x;
            acc.y += w0 * h0.y;
            acc.z += w0 * h0.z;
            acc.w += w0 * h0.w;
            den += w0;
        }
        const float inv = 1.f / den;
        float4 r;
        r.x = fmaxf(acc.x * inv + bv.x, 0.f);
        r.y = fmaxf(acc.y * inv + bv.y, 0.f);
        r.z = fmaxf(acc.z * inv + bv.z, 0.f);
        r.w = fmaxf(acc.w * inv + bv.w, 0.f);
        *reinterpret_cast<float4*>(&out[(size_t)d * IN_FEAT + lane * 4]) = r;
    }
}

extern "C" void kernel_launch(void* const* d_in, const int* in_sizes, int n_in,
                              void* d_out, int out_size, void* d_ws, size_t ws_size,
                              hipStream_t stream) {
    const float* x       = (const float*)d_in[0];
    const int*   ei      = (const int*)d_in[1];      // harness converts int64 -> int32
    const float* W       = (const float*)d_in[2];
    const float* att_src = (const float*)d_in[3];
    const float* att_dst = (const float*)d_in[4];
    const float* bias    = (const float*)d_in[5];
    float*       out     = (float*)d_out;

    const int N = in_sizes[0] / IN_FEAT;   // 50000
    const int E = in_sizes[1] / 2;         // 800000

    // workspace layout (floats/ints are both 4B)
    float* H          = (float*)d_ws;                    // N*256
    float* asrc       = H + (size_t)N * IN_FEAT;         // N*4
    float* adst       = asrc + (size_t)N * HEADS;        // N*4
    int*   counts     = (int*)(adst + (size_t)N * HEADS);// N
    int*   offsets    = counts + N;                      // N
    int*   cursor     = offsets + N;                     // N
    int*   sorted_src = cursor + N;                      // E

    // CSR build
    zero_counts<<<256, 256, 0, stream>>>(counts, N);
    hist_kernel<<<2048, 256, 0, stream>>>(ei, counts, E, N);
    scan_kernel<<<1, 1024, 0, stream>>>(counts, offsets, cursor, N);
    scatter_kernel<<<2048, 256, 0, stream>>>(ei, cursor, sorted_src, E, N);

    // projection + logits
    {
        dim3 grid((N + 63) / 64, IN_FEAT / 64);
        gemm_f32<<<grid, 256, 0, stream>>>(x, W, H, N);
    }
    node_logits<<<1024, 256, 0, stream>>>(H, att_src, att_dst, asrc, adst, N);

    // gather aggregation (no atomics)
    aggregate<<<(N * 64 + 255) / 256, 256, 0, stream>>>(H, asrc, adst, offsets, counts,
                                                        sorted_src, bias, out, N);
}

// Round 4
// 386.597 us; speedup vs baseline: 7.6614x; 1.3761x over previous
//
#include <hip/hip_runtime.h>
#include <hip/hip_bf16.h>

#define IN_FEAT 256
#define HEADS 4
#define OUT_FEAT 64
#define NEG_SLOPE 0.2f

typedef __bf16 bf16x8 __attribute__((ext_vector_type(8)));
typedef float f32x4 __attribute__((ext_vector_type(4)));

__device__ inline unsigned short f2bf(float f) {
    union { float f; unsigned u; } v; v.f = f;
    unsigned r = v.u + 0x7FFF + ((v.u >> 16) & 1);   // RNE, finite inputs
    return (unsigned short)(r >> 16);
}

// ---------------- CSR build --------------------------------------------------
__global__ void zero_counts(int* __restrict__ counts, int n) {
    int idx = blockIdx.x * blockDim.x + threadIdx.x;
    int stride = gridDim.x * blockDim.x;
    for (int i = idx; i < n; i += stride) counts[i] = 0;
}

__global__ void hist_kernel(const int* __restrict__ ei, int* __restrict__ counts,
                            int E, int N) {
    int idx = blockIdx.x * blockDim.x + threadIdx.x;
    int stride = gridDim.x * blockDim.x;
    for (int e = idx; e < E; e += stride) {
        int d = ei[E + e];
        if ((unsigned)d < (unsigned)N) atomicAdd(&counts[d], 1);
    }
}

__global__ __launch_bounds__(1024) void scan_kernel(const int* __restrict__ counts,
                                                    int* __restrict__ offsets,
                                                    int* __restrict__ cursor, int N) {
    __shared__ int sdata[1024];
    const int t = threadIdx.x;
    const int chunk = (N + 1023) / 1024;
    const int begin = t * chunk;
    const int endi = min(begin + chunk, N);
    int sum = 0;
    for (int i = begin; i < endi; ++i) sum += counts[i];
    sdata[t] = sum;
    __syncthreads();
    for (int off = 1; off < 1024; off <<= 1) {
        int v = (t >= off) ? sdata[t - off] : 0;
        __syncthreads();
        sdata[t] += v;
        __syncthreads();
    }
    int run = (t == 0) ? 0 : sdata[t - 1];
    for (int i = begin; i < endi; ++i) {
        offsets[i] = run;
        cursor[i] = run;
        run += counts[i];
    }
}

__global__ void scatter_kernel(const int* __restrict__ ei, int* __restrict__ cursor,
                               int* __restrict__ sorted_src, int E, int N) {
    int idx = blockIdx.x * blockDim.x + threadIdx.x;
    int stride = gridDim.x * blockDim.x;
    for (int e = idx; e < E; e += stride) {
        int s = ei[e];
        int d = ei[E + e];
        if ((unsigned)s >= (unsigned)N || (unsigned)d >= (unsigned)N) continue;
        int pos = atomicAdd(&cursor[d], 1);
        sorted_src[pos] = s;
    }
}

// ---------------- W -> Wt (transposed, bf16) --------------------------------
__global__ void cvt_w(const float* __restrict__ W, unsigned short* __restrict__ Wtb) {
    int idx = blockIdx.x * blockDim.x + threadIdx.x;   // 65536
    int k = idx >> 8, n = idx & 255;
    Wtb[n * 256 + k] = f2bf(W[k * 256 + n]);
}

// ---------------- H = x @ W via bf16 MFMA -----------------------------------
// 128x64 tile, BK=128 (2 K-chunks), 4 waves each computing 32x64.
// LDS tiles XOR-swizzled (byte ^= (row&7)<<4) to kill ds_read_b128 conflicts.
__global__ __launch_bounds__(256) void gemm_mfma(const float* __restrict__ X,
                                                 const unsigned short* __restrict__ Wtb,
                                                 float* __restrict__ H, int M) {
    __shared__ __align__(16) unsigned short sA[128 * 128];  // 32 KB
    __shared__ __align__(16) unsigned short sB[64 * 128];   // 16 KB
    const int bx = blockIdx.x;
    const int bm = (bx >> 2) * 128;
    const int bn = (bx & 3) * 64;
    const int tid = threadIdx.x;
    const int lane = tid & 63;
    const int wid = tid >> 6;

    f32x4 acc[2][4] = {};

    for (int k0 = 0; k0 < IN_FEAT; k0 += 128) {
        __syncthreads();   // previous chunk's reads complete
        // ---- stage A: f32 -> bf16, swizzled ds_write (4096 float4s) ----
#pragma unroll
        for (int it = 0; it < 16; ++it) {
            int f4 = it * 256 + tid;        // float4 id
            int row = f4 >> 5;              // 32 float4 per row
            int c4 = f4 & 31;
            int gr = bm + row;
            float4 v = make_float4(0.f, 0.f, 0.f, 0.f);
            if (gr < M)
                v = *reinterpret_cast<const float4*>(&X[(size_t)gr * IN_FEAT + k0 + c4 * 4]);
            int c = c4 >> 1, half = c4 & 1;
            int sidx = row * 128 + ((c ^ (row & 7)) << 3) + half * 4;
            ushort4 p;
            p.x = f2bf(v.x); p.y = f2bf(v.y); p.z = f2bf(v.z); p.w = f2bf(v.w);
            *reinterpret_cast<ushort4*>(&sA[sidx]) = p;
        }
        // ---- stage B: bf16 16B chunks, swizzled (1024 chunks) ----
#pragma unroll
        for (int it = 0; it < 4; ++it) {
            int o = it * 256 + tid;         // 16B-chunk id
            int row = o >> 4;               // 16 chunks per row
            int c = o & 15;
            uint4 v = *reinterpret_cast<const uint4*>(
                &Wtb[(size_t)(bn + row) * 256 + k0 + c * 8]);
            int sidx = row * 128 + ((c ^ (row & 7)) << 3);
            *reinterpret_cast<uint4*>(&sB[sidx]) = v;
        }
        __syncthreads();
        // ---- MFMA over this K-chunk ----
#pragma unroll
        for (int kk = 0; kk < 4; ++kk) {
            bf16x8 af[2], bfr[4];
#pragma unroll
            for (int m = 0; m < 2; ++m) {
                int r = wid * 32 + m * 16 + (lane & 15);
                int cc = (kk * 4 + (lane >> 4)) ^ (r & 7);
                af[m] = *reinterpret_cast<const bf16x8*>(&sA[r * 128 + cc * 8]);
            }
#pragma unroll
            for (int nf = 0; nf < 4; ++nf) {
                int r = nf * 16 + (lane & 15);
                int cc = (kk * 4 + (lane >> 4)) ^ (r & 7);
                bfr[nf] = *reinterpret_cast<const bf16x8*>(&sB[r * 128 + cc * 8]);
            }
#pragma unroll
            for (int m = 0; m < 2; ++m)
#pragma unroll
                for (int nf = 0; nf < 4; ++nf)
                    acc[m][nf] = __builtin_amdgcn_mfma_f32_16x16x32_bf16(
                        af[m], bfr[nf], acc[m][nf], 0, 0, 0);
        }
    }
    // ---- store C (verified layout: col=lane&15, row=(lane>>4)*4+i) ----
#pragma unroll
    for (int m = 0; m < 2; ++m)
#pragma unroll
        for (int i = 0; i < 4; ++i) {
            int R = bm + wid * 32 + m * 16 + ((lane >> 4) << 2) + i;
            if (R < M) {
#pragma unroll
                for (int nf = 0; nf < 4; ++nf)
                    H[(size_t)R * IN_FEAT + bn + nf * 16 + (lane & 15)] = acc[m][nf][i];
            }
        }
}

// ---------------- per-node attention logits ---------------------------------
__global__ void node_logits(const float* __restrict__ H,
                            const float* __restrict__ att_src,
                            const float* __restrict__ att_dst,
                            float* __restrict__ asrc, float* __restrict__ adst,
                            int N) {
    int gtid = blockIdx.x * blockDim.x + threadIdx.x;
    int wave = gtid >> 6;
    int lane = threadIdx.x & 63;
    int nwaves = (gridDim.x * blockDim.x) >> 6;
    const float4 as = *reinterpret_cast<const float4*>(&att_src[lane * 4]);
    const float4 ad = *reinterpret_cast<const float4*>(&att_dst[lane * 4]);
    for (int i = wave; i < N; i += nwaves) {
        const float4 hv = *reinterpret_cast<const float4*>(&H[(size_t)i * IN_FEAT + lane * 4]);
        float ps = hv.x * as.x + hv.y * as.y + hv.z * as.z + hv.w * as.w;
        float pd = hv.x * ad.x + hv.y * ad.y + hv.z * ad.z + hv.w * ad.w;
#pragma unroll
        for (int off = 1; off < 16; off <<= 1) {
            ps += __shfl_xor(ps, off, 64);
            pd += __shfl_xor(pd, off, 64);
        }
        if ((lane & 15) == 0) {
            int head = lane >> 4;
            asrc[i * HEADS + head] = ps;
            adst[i * HEADS + head] = pd;
        }
    }
}

// ---------------- gather aggregate: one wave per destination node -----------
__global__ __launch_bounds__(256) void aggregate(const float* __restrict__ H,
                                                 const float* __restrict__ asrc,
                                                 const float* __restrict__ adst,
                                                 const int* __restrict__ offsets,
                                                 const int* __restrict__ counts,
                                                 const int* __restrict__ sorted_src,
                                                 const float* __restrict__ bias,
                                                 float* __restrict__ out, int N) {
    int gtid = blockIdx.x * blockDim.x + threadIdx.x;
    int wave = gtid >> 6;
    int lane = threadIdx.x & 63;
    int nwaves = (gridDim.x * blockDim.x) >> 6;
    int head = lane >> 4;
    const float4 bv = *reinterpret_cast<const float4*>(&bias[lane * 4]);
    for (int d = wave; d < N; d += nwaves) {
        const float ad = adst[d * HEADS + head];
        float a = asrc[d * HEADS + head] + ad;
        float w = __expf((a > 0.f) ? a : NEG_SLOPE * a);
        const float4 hvd = *reinterpret_cast<const float4*>(&H[(size_t)d * IN_FEAT + lane * 4]);
        float4 acc = make_float4(w * hvd.x, w * hvd.y, w * hvd.z, w * hvd.w);
        float den = w;
        const int start = offsets[d];
        const int cnt = counts[d];
        int k = 0;
        for (; k + 1 < cnt; k += 2) {
            int s0 = sorted_src[start + k];
            int s1 = sorted_src[start + k + 1];
            float a0 = asrc[s0 * HEADS + head] + ad;
            float a1 = asrc[s1 * HEADS + head] + ad;
            const float4 h0 = *reinterpret_cast<const float4*>(&H[(size_t)s0 * IN_FEAT + lane * 4]);
            const float4 h1 = *reinterpret_cast<const float4*>(&H[(size_t)s1 * IN_FEAT + lane * 4]);
            float w0 = __expf((a0 > 0.f) ? a0 : NEG_SLOPE * a0);
            float w1 = __expf((a1 > 0.f) ? a1 : NEG_SLOPE * a1);
            acc.x += w0 * h0.x + w1 * h1.x;
            acc.y += w0 * h0.y + w1 * h1.y;
            acc.z += w0 * h0.z + w1 * h1.z;
            acc.w += w0 * h0.w + w1 * h1.w;
            den += w0 + w1;
        }
        if (k < cnt) {
            int s0 = sorted_src[start + k];
            float a0 = asrc[s0 * HEADS + head] + ad;
            const float4 h0 = *reinterpret_cast<const float4*>(&H[(size_t)s0 * IN_FEAT + lane * 4]);
            float w0 = __expf((a0 > 0.f) ? a0 : NEG_SLOPE * a0);
            acc.x += w0 * h0.x;
            acc.y += w0 * h0.y;
            acc.z += w0 * h0.z;
            acc.w += w0 * h0.w;
            den += w0;
        }
        const float inv = 1.f / den;
        float4 r;
        r.x = fmaxf(acc.x * inv + bv.x, 0.f);
        r.y = fmaxf(acc.y * inv + bv.y, 0.f);
        r.z = fmaxf(acc.z * inv + bv.z, 0.f);
        r.w = fmaxf(acc.w * inv + bv.w, 0.f);
        *reinterpret_cast<float4*>(&out[(size_t)d * IN_FEAT + lane * 4]) = r;
    }
}

extern "C" void kernel_launch(void* const* d_in, const int* in_sizes, int n_in,
                              void* d_out, int out_size, void* d_ws, size_t ws_size,
                              hipStream_t stream) {
    const float* x       = (const float*)d_in[0];
    const int*   ei      = (const int*)d_in[1];      // harness converts int64 -> int32
    const float* W       = (const float*)d_in[2];
    const float* att_src = (const float*)d_in[3];
    const float* att_dst = (const float*)d_in[4];
    const float* bias    = (const float*)d_in[5];
    float*       out     = (float*)d_out;

    const int N = in_sizes[0] / IN_FEAT;   // 50000
    const int E = in_sizes[1] / 2;         // 800000

    // workspace layout (4B elements)
    float* H          = (float*)d_ws;                    // N*256
    float* asrc       = H + (size_t)N * IN_FEAT;         // N*4
    float* adst       = asrc + (size_t)N * HEADS;        // N*4
    int*   counts     = (int*)(adst + (size_t)N * HEADS);// N
    int*   offsets    = counts + N;                      // N
    int*   cursor     = offsets + N;                     // N
    int*   sorted_src = cursor + N;                      // E
    unsigned short* Wtb = (unsigned short*)(sorted_src + E); // 256*256 bf16

    // CSR build
    zero_counts<<<256, 256, 0, stream>>>(counts, N);
    hist_kernel<<<2048, 256, 0, stream>>>(ei, counts, E, N);
    scan_kernel<<<1, 1024, 0, stream>>>(counts, offsets, cursor, N);
    scatter_kernel<<<2048, 256, 0, stream>>>(ei, cursor, sorted_src, E, N);

    // projection + logits
    cvt_w<<<256, 256, 0, stream>>>(W, Wtb);
    {
        int mtiles = (N + 127) / 128;
        gemm_mfma<<<mtiles * 4, 256, 0, stream>>>(x, Wtb, H, N);
    }
    node_logits<<<1024, 256, 0, stream>>>(H, att_src, att_dst, asrc, adst, N);

    // gather aggregation (no atomics)
    aggregate<<<(N * 64 + 255) / 256, 256, 0, stream>>>(H, asrc, adst, offsets, counts,
                                                        sorted_src, bias, out, N);
}

// Round 5
// 336.281 us; speedup vs baseline: 8.8078x; 1.1496x over previous
//
#include <hip/hip_runtime.h>
#include <hip/hip_bf16.h>

#define IN_FEAT 256
#define HEADS 4
#define OUT_FEAT 64
#define NEG_SLOPE 0.2f

typedef __bf16 bf16x8 __attribute__((ext_vector_type(8)));
typedef float f32x4 __attribute__((ext_vector_type(4)));

__device__ inline unsigned short f2bf(float f) {
    union { float f; unsigned u; } v; v.f = f;
    unsigned r = v.u + 0x7FFF + ((v.u >> 16) & 1);   // RNE, finite inputs
    return (unsigned short)(r >> 16);
}
__device__ inline float bf2f(unsigned short u) {
    union { unsigned u; float f; } v; v.u = ((unsigned)u) << 16; return v.f;
}

// ---------------- CSR build --------------------------------------------------
__global__ void zero_counts(int* __restrict__ counts, int n) {
    int idx = blockIdx.x * blockDim.x + threadIdx.x;
    int stride = gridDim.x * blockDim.x;
    for (int i = idx; i < n; i += stride) counts[i] = 0;
}

__global__ void hist_kernel(const int* __restrict__ ei, int* __restrict__ counts,
                            int E, int N) {
    int idx = blockIdx.x * blockDim.x + threadIdx.x;
    int stride = gridDim.x * blockDim.x;
    for (int e = idx; e < E; e += stride) {
        int d = ei[E + e];
        if ((unsigned)d < (unsigned)N) atomicAdd(&counts[d], 1);
    }
}

__global__ __launch_bounds__(1024) void scan_kernel(const int* __restrict__ counts,
                                                    int* __restrict__ offsets,
                                                    int* __restrict__ cursor, int N) {
    __shared__ int sdata[1024];
    const int t = threadIdx.x;
    const int chunk = (N + 1023) / 1024;
    const int begin = t * chunk;
    const int endi = min(begin + chunk, N);
    int sum = 0;
    for (int i = begin; i < endi; ++i) sum += counts[i];
    sdata[t] = sum;
    __syncthreads();
    for (int off = 1; off < 1024; off <<= 1) {
        int v = (t >= off) ? sdata[t - off] : 0;
        __syncthreads();
        sdata[t] += v;
        __syncthreads();
    }
    int run = (t == 0) ? 0 : sdata[t - 1];
    for (int i = begin; i < endi; ++i) {
        offsets[i] = run;
        cursor[i] = run;
        run += counts[i];
    }
}

__global__ void scatter_kernel(const int* __restrict__ ei, int* __restrict__ cursor,
                               int* __restrict__ sorted_src, int E, int N) {
    int idx = blockIdx.x * blockDim.x + threadIdx.x;
    int stride = gridDim.x * blockDim.x;
    for (int e = idx; e < E; e += stride) {
        int s = ei[e];
        int d = ei[E + e];
        if ((unsigned)s >= (unsigned)N || (unsigned)d >= (unsigned)N) continue;
        int pos = atomicAdd(&cursor[d], 1);
        sorted_src[pos] = s;
    }
}

// ---------------- W -> Wt (transposed, bf16) --------------------------------
__global__ void cvt_w(const float* __restrict__ W, unsigned short* __restrict__ Wtb) {
    int idx = blockIdx.x * blockDim.x + threadIdx.x;   // 65536
    int k = idx >> 8, n = idx & 255;
    Wtb[n * 256 + k] = f2bf(W[k * 256 + n]);
}

// ---------------- Hb = bf16(x @ W), fused per-head logits -------------------
// 128x64 tile, BK=128; each bn slice (64 cols) == one head, so the block
// computes that head's a_src/a_dst for its 128 rows from the C fragments.
__global__ __launch_bounds__(256) void gemm_mfma(const float* __restrict__ X,
                                                 const unsigned short* __restrict__ Wtb,
                                                 const float* __restrict__ att_src,
                                                 const float* __restrict__ att_dst,
                                                 unsigned short* __restrict__ Hb,
                                                 float* __restrict__ asrc,
                                                 float* __restrict__ adst, int M) {
    __shared__ __align__(16) unsigned short sA[128 * 128];  // 32 KB
    __shared__ __align__(16) unsigned short sB[64 * 128];   // 16 KB
    const int bx = blockIdx.x;
    const int bm = (bx >> 2) * 128;
    const int bn = (bx & 3) * 64;
    const int h0 = bn >> 6;
    const int tid = threadIdx.x;
    const int lane = tid & 63;
    const int wid = tid >> 6;

    f32x4 acc[2][4] = {};

    for (int k0 = 0; k0 < IN_FEAT; k0 += 128) {
        __syncthreads();
        // ---- stage A: f32 -> bf16, swizzled ds_write ----
#pragma unroll
        for (int it = 0; it < 16; ++it) {
            int f4 = it * 256 + tid;
            int row = f4 >> 5;
            int c4 = f4 & 31;
            int gr = bm + row;
            float4 v = make_float4(0.f, 0.f, 0.f, 0.f);
            if (gr < M)
                v = *reinterpret_cast<const float4*>(&X[(size_t)gr * IN_FEAT + k0 + c4 * 4]);
            int c = c4 >> 1, half = c4 & 1;
            int sidx = row * 128 + ((c ^ (row & 7)) << 3) + half * 4;
            ushort4 p;
            p.x = f2bf(v.x); p.y = f2bf(v.y); p.z = f2bf(v.z); p.w = f2bf(v.w);
            *reinterpret_cast<ushort4*>(&sA[sidx]) = p;
        }
        // ---- stage B ----
#pragma unroll
        for (int it = 0; it < 4; ++it) {
            int o = it * 256 + tid;
            int row = o >> 4;
            int c = o & 15;
            uint4 v = *reinterpret_cast<const uint4*>(
                &Wtb[(size_t)(bn + row) * 256 + k0 + c * 8]);
            int sidx = row * 128 + ((c ^ (row & 7)) << 3);
            *reinterpret_cast<uint4*>(&sB[sidx]) = v;
        }
        __syncthreads();
        // ---- MFMA ----
#pragma unroll
        for (int kk = 0; kk < 4; ++kk) {
            bf16x8 af[2], bfr[4];
#pragma unroll
            for (int m = 0; m < 2; ++m) {
                int r = wid * 32 + m * 16 + (lane & 15);
                int cc = (kk * 4 + (lane >> 4)) ^ (r & 7);
                af[m] = *reinterpret_cast<const bf16x8*>(&sA[r * 128 + cc * 8]);
            }
#pragma unroll
            for (int nf = 0; nf < 4; ++nf) {
                int r = nf * 16 + (lane & 15);
                int cc = (kk * 4 + (lane >> 4)) ^ (r & 7);
                bfr[nf] = *reinterpret_cast<const bf16x8*>(&sB[r * 128 + cc * 8]);
            }
#pragma unroll
            for (int m = 0; m < 2; ++m)
#pragma unroll
                for (int nf = 0; nf < 4; ++nf)
                    acc[m][nf] = __builtin_amdgcn_mfma_f32_16x16x32_bf16(
                        af[m], bfr[nf], acc[m][nf], 0, 0, 0);
        }
    }
    // ---- epilogue: bf16 store + fused per-head logits ----
    float attS[4], attD[4];
#pragma unroll
    for (int nf = 0; nf < 4; ++nf) {
        attS[nf] = att_src[h0 * 64 + nf * 16 + (lane & 15)];
        attD[nf] = att_dst[h0 * 64 + nf * 16 + (lane & 15)];
    }
#pragma unroll
    for (int m = 0; m < 2; ++m)
#pragma unroll
        for (int i = 0; i < 4; ++i) {
            int R = bm + wid * 32 + m * 16 + ((lane >> 4) << 2) + i;
            float ps = 0.f, pd = 0.f;
#pragma unroll
            for (int nf = 0; nf < 4; ++nf) {
                float v = acc[m][nf][i];
                ps += v * attS[nf];
                pd += v * attD[nf];
                if (R < M)
                    Hb[(size_t)R * IN_FEAT + bn + nf * 16 + (lane & 15)] = f2bf(v);
            }
#pragma unroll
            for (int off = 1; off < 16; off <<= 1) {
                ps += __shfl_xor(ps, off, 64);
                pd += __shfl_xor(pd, off, 64);
            }
            if ((lane & 15) == 0 && R < M) {
                asrc[R * HEADS + h0] = ps;
                adst[R * HEADS + h0] = pd;
            }
        }
}

// ---------------- gather aggregate: one wave per destination node -----------
__global__ __launch_bounds__(256) void aggregate(const unsigned short* __restrict__ Hb,
                                                 const float* __restrict__ asrc,
                                                 const float* __restrict__ adst,
                                                 const int* __restrict__ offsets,
                                                 const int* __restrict__ counts,
                                                 const int* __restrict__ sorted_src,
                                                 const float* __restrict__ bias,
                                                 float* __restrict__ out, int N) {
    int gtid = blockIdx.x * blockDim.x + threadIdx.x;
    int wave = gtid >> 6;
    int lane = threadIdx.x & 63;
    int nwaves = (gridDim.x * blockDim.x) >> 6;
    int head = lane >> 4;
    const float4 bv = *reinterpret_cast<const float4*>(&bias[lane * 4]);
    for (int d = wave; d < N; d += nwaves) {
        const float ad = adst[d * HEADS + head];
        float a = asrc[d * HEADS + head] + ad;
        float w = __expf((a > 0.f) ? a : NEG_SLOPE * a);
        ushort4 ud = *reinterpret_cast<const ushort4*>(&Hb[(size_t)d * IN_FEAT + lane * 4]);
        float4 acc = make_float4(w * bf2f(ud.x), w * bf2f(ud.y),
                                 w * bf2f(ud.z), w * bf2f(ud.w));
        float den = w;
        const int start = offsets[d];
        const int cnt = counts[d];
        int k = 0;
        for (; k + 3 < cnt; k += 4) {
            int s0 = sorted_src[start + k + 0];
            int s1 = sorted_src[start + k + 1];
            int s2 = sorted_src[start + k + 2];
            int s3 = sorted_src[start + k + 3];
            float a0 = asrc[s0 * HEADS + head] + ad;
            float a1 = asrc[s1 * HEADS + head] + ad;
            float a2 = asrc[s2 * HEADS + head] + ad;
            float a3 = asrc[s3 * HEADS + head] + ad;
            ushort4 u0 = *reinterpret_cast<const ushort4*>(&Hb[(size_t)s0 * IN_FEAT + lane * 4]);
            ushort4 u1 = *reinterpret_cast<const ushort4*>(&Hb[(size_t)s1 * IN_FEAT + lane * 4]);
            ushort4 u2 = *reinterpret_cast<const ushort4*>(&Hb[(size_t)s2 * IN_FEAT + lane * 4]);
            ushort4 u3 = *reinterpret_cast<const ushort4*>(&Hb[(size_t)s3 * IN_FEAT + lane * 4]);
            float w0 = __expf((a0 > 0.f) ? a0 : NEG_SLOPE * a0);
            float w1 = __expf((a1 > 0.f) ? a1 : NEG_SLOPE * a1);
            float w2 = __expf((a2 > 0.f) ? a2 : NEG_SLOPE * a2);
            float w3 = __expf((a3 > 0.f) ? a3 : NEG_SLOPE * a3);
            acc.x += w0 * bf2f(u0.x) + w1 * bf2f(u1.x) + w2 * bf2f(u2.x) + w3 * bf2f(u3.x);
            acc.y += w0 * bf2f(u0.y) + w1 * bf2f(u1.y) + w2 * bf2f(u2.y) + w3 * bf2f(u3.y);
            acc.z += w0 * bf2f(u0.z) + w1 * bf2f(u1.z) + w2 * bf2f(u2.z) + w3 * bf2f(u3.z);
            acc.w += w0 * bf2f(u0.w) + w1 * bf2f(u1.w) + w2 * bf2f(u2.w) + w3 * bf2f(u3.w);
            den += w0 + w1 + w2 + w3;
        }
        for (; k < cnt; ++k) {
            int s0 = sorted_src[start + k];
            float a0 = asrc[s0 * HEADS + head] + ad;
            ushort4 u0 = *reinterpret_cast<const ushort4*>(&Hb[(size_t)s0 * IN_FEAT + lane * 4]);
            float w0 = __expf((a0 > 0.f) ? a0 : NEG_SLOPE * a0);
            acc.x += w0 * bf2f(u0.x);
            acc.y += w0 * bf2f(u0.y);
            acc.z += w0 * bf2f(u0.z);
            acc.w += w0 * bf2f(u0.w);
            den += w0;
        }
        const float inv = 1.f / den;
        float4 r;
        r.x = fmaxf(acc.x * inv + bv.x, 0.f);
        r.y = fmaxf(acc.y * inv + bv.y, 0.f);
        r.z = fmaxf(acc.z * inv + bv.z, 0.f);
        r.w = fmaxf(acc.w * inv + bv.w, 0.f);
        *reinterpret_cast<float4*>(&out[(size_t)d * IN_FEAT + lane * 4]) = r;
    }
}

extern "C" void kernel_launch(void* const* d_in, const int* in_sizes, int n_in,
                              void* d_out, int out_size, void* d_ws, size_t ws_size,
                              hipStream_t stream) {
    const float* x       = (const float*)d_in[0];
    const int*   ei      = (const int*)d_in[1];      // harness converts int64 -> int32
    const float* W       = (const float*)d_in[2];
    const float* att_src = (const float*)d_in[3];
    const float* att_dst = (const float*)d_in[4];
    const float* bias    = (const float*)d_in[5];
    float*       out     = (float*)d_out;

    const int N = in_sizes[0] / IN_FEAT;   // 50000
    const int E = in_sizes[1] / 2;         // 800000

    // workspace layout (4B elements unless noted)
    unsigned short* Hb  = (unsigned short*)d_ws;          // N*256 bf16
    float* asrc       = (float*)(Hb + (size_t)N * IN_FEAT);
    float* adst       = asrc + (size_t)N * HEADS;
    int*   counts     = (int*)(adst + (size_t)N * HEADS);
    int*   offsets    = counts + N;
    int*   cursor     = offsets + N;
    int*   sorted_src = cursor + N;                       // E
    unsigned short* Wtb = (unsigned short*)(sorted_src + E); // 256*256 bf16

    // CSR build
    zero_counts<<<256, 256, 0, stream>>>(counts, N);
    hist_kernel<<<2048, 256, 0, stream>>>(ei, counts, E, N);
    scan_kernel<<<1, 1024, 0, stream>>>(counts, offsets, cursor, N);
    scatter_kernel<<<2048, 256, 0, stream>>>(ei, cursor, sorted_src, E, N);

    // projection + fused logits
    cvt_w<<<256, 256, 0, stream>>>(W, Wtb);
    {
        int mtiles = (N + 127) / 128;
        gemm_mfma<<<mtiles * 4, 256, 0, stream>>>(x, Wtb, att_src, att_dst,
                                                  Hb, asrc, adst, N);
    }

    // gather aggregation (no atomics)
    aggregate<<<(N * 64 + 255) / 256, 256, 0, stream>>>(Hb, asrc, adst, offsets, counts,
                                                        sorted_src, bias, out, N);
}

// Round 6
// 232.995 us; speedup vs baseline: 12.7122x; 1.4433x over previous
//
#include <hip/hip_runtime.h>
#include <hip/hip_bf16.h>

#define IN_FEAT 256
#define HEADS 4
#define OUT_FEAT 64
#define NEG_SLOPE 0.2f

typedef __bf16 bf16x8 __attribute__((ext_vector_type(8)));
typedef float f32x4 __attribute__((ext_vector_type(4)));

__device__ inline unsigned short f2bf(float f) {
    union { float f; unsigned u; } v; v.f = f;
    unsigned r = v.u + 0x7FFF + ((v.u >> 16) & 1);   // RNE, finite inputs
    return (unsigned short)(r >> 16);
}
__device__ inline float bf2f(unsigned short u) {
    union { unsigned u; float f; } v; v.u = ((unsigned)u) << 16; return v.f;
}

// ---------------- CSR build --------------------------------------------------
__global__ void zero_counts(int* __restrict__ counts, int n, int* __restrict__ gcur) {
    int idx = blockIdx.x * blockDim.x + threadIdx.x;
    int stride = gridDim.x * blockDim.x;
    for (int i = idx; i < n; i += stride) counts[i] = 0;
    if (blockIdx.x == 0 && threadIdx.x == 0) *gcur = 0;
}

__global__ void hist_kernel(const int* __restrict__ ei, int* __restrict__ counts,
                            int E, int N) {
    int idx = blockIdx.x * blockDim.x + threadIdx.x;
    int stride = gridDim.x * blockDim.x;
    for (int e = idx; e < E; e += stride) {
        int d = ei[E + e];
        if ((unsigned)d < (unsigned)N) atomicAdd(&counts[d], 1);
    }
}

// Parallel "scan": per-1024 tile local exclusive scan; tile base reserved via
// one atomicAdd on a global cursor. Segment ORDER is irrelevant for CSR use —
// only disjointness + size matter.
__global__ __launch_bounds__(1024) void scan_atomic(const int* __restrict__ counts,
                                                    int* __restrict__ offsets,
                                                    int* __restrict__ cursor,
                                                    int* __restrict__ gcur, int N) {
    __shared__ int sdata[1024];
    __shared__ int sbase;
    const int t = threadIdx.x;
    const int i = blockIdx.x * 1024 + t;
    const int v = (i < N) ? counts[i] : 0;
    sdata[t] = v;
    __syncthreads();
    for (int off = 1; off < 1024; off <<= 1) {
        int u = (t >= off) ? sdata[t - off] : 0;
        __syncthreads();
        sdata[t] += u;
        __syncthreads();
    }
    if (t == 1023) sbase = atomicAdd(gcur, sdata[1023]);
    __syncthreads();
    if (i < N) {
        int excl = sbase + sdata[t] - v;
        offsets[i] = excl;
        cursor[i] = excl;
    }
}

__global__ void scatter_kernel(const int* __restrict__ ei, int* __restrict__ cursor,
                               int* __restrict__ sorted_src, int E, int N) {
    int idx = blockIdx.x * blockDim.x + threadIdx.x;
    int stride = gridDim.x * blockDim.x;
    for (int e = idx; e < E; e += stride) {
        int s = ei[e];
        int d = ei[E + e];
        if ((unsigned)s >= (unsigned)N || (unsigned)d >= (unsigned)N) continue;
        int pos = atomicAdd(&cursor[d], 1);
        sorted_src[pos] = s;
    }
}

// ---------------- W -> Wt (transposed, bf16) --------------------------------
__global__ void cvt_w(const float* __restrict__ W, unsigned short* __restrict__ Wtb) {
    int idx = blockIdx.x * blockDim.x + threadIdx.x;   // 65536
    int k = idx >> 8, n = idx & 255;
    Wtb[n * 256 + k] = f2bf(W[k * 256 + n]);
}

// ---------------- Hb = bf16(x @ W), fused per-head logits -------------------
__global__ __launch_bounds__(256) void gemm_mfma(const float* __restrict__ X,
                                                 const unsigned short* __restrict__ Wtb,
                                                 const float* __restrict__ att_src,
                                                 const float* __restrict__ att_dst,
                                                 unsigned short* __restrict__ Hb,
                                                 float* __restrict__ asrc,
                                                 float* __restrict__ adst, int M) {
    __shared__ __align__(16) unsigned short sA[128 * 128];  // 32 KB
    __shared__ __align__(16) unsigned short sB[64 * 128];   // 16 KB
    const int bx = blockIdx.x;
    const int bm = (bx >> 2) * 128;
    const int bn = (bx & 3) * 64;
    const int h0 = bn >> 6;
    const int tid = threadIdx.x;
    const int lane = tid & 63;
    const int wid = tid >> 6;

    f32x4 acc[2][4] = {};

    for (int k0 = 0; k0 < IN_FEAT; k0 += 128) {
        __syncthreads();
        // ---- stage A: f32 -> bf16, swizzled ds_write ----
#pragma unroll
        for (int it = 0; it < 16; ++it) {
            int f4 = it * 256 + tid;
            int row = f4 >> 5;
            int c4 = f4 & 31;
            int gr = bm + row;
            float4 v = make_float4(0.f, 0.f, 0.f, 0.f);
            if (gr < M)
                v = *reinterpret_cast<const float4*>(&X[(size_t)gr * IN_FEAT + k0 + c4 * 4]);
            int c = c4 >> 1, half = c4 & 1;
            int sidx = row * 128 + ((c ^ (row & 7)) << 3) + half * 4;
            ushort4 p;
            p.x = f2bf(v.x); p.y = f2bf(v.y); p.z = f2bf(v.z); p.w = f2bf(v.w);
            *reinterpret_cast<ushort4*>(&sA[sidx]) = p;
        }
        // ---- stage B ----
#pragma unroll
        for (int it = 0; it < 4; ++it) {
            int o = it * 256 + tid;
            int row = o >> 4;
            int c = o & 15;
            uint4 v = *reinterpret_cast<const uint4*>(
                &Wtb[(size_t)(bn + row) * 256 + k0 + c * 8]);
            int sidx = row * 128 + ((c ^ (row & 7)) << 3);
            *reinterpret_cast<uint4*>(&sB[sidx]) = v;
        }
        __syncthreads();
        // ---- MFMA ----
#pragma unroll
        for (int kk = 0; kk < 4; ++kk) {
            bf16x8 af[2], bfr[4];
#pragma unroll
            for (int m = 0; m < 2; ++m) {
                int r = wid * 32 + m * 16 + (lane & 15);
                int cc = (kk * 4 + (lane >> 4)) ^ (r & 7);
                af[m] = *reinterpret_cast<const bf16x8*>(&sA[r * 128 + cc * 8]);
            }
#pragma unroll
            for (int nf = 0; nf < 4; ++nf) {
                int r = nf * 16 + (lane & 15);
                int cc = (kk * 4 + (lane >> 4)) ^ (r & 7);
                bfr[nf] = *reinterpret_cast<const bf16x8*>(&sB[r * 128 + cc * 8]);
            }
#pragma unroll
            for (int m = 0; m < 2; ++m)
#pragma unroll
                for (int nf = 0; nf < 4; ++nf)
                    acc[m][nf] = __builtin_amdgcn_mfma_f32_16x16x32_bf16(
                        af[m], bfr[nf], acc[m][nf], 0, 0, 0);
        }
    }
    // ---- epilogue: bf16 store + fused per-head logits ----
    float attS[4], attD[4];
#pragma unroll
    for (int nf = 0; nf < 4; ++nf) {
        attS[nf] = att_src[h0 * 64 + nf * 16 + (lane & 15)];
        attD[nf] = att_dst[h0 * 64 + nf * 16 + (lane & 15)];
    }
#pragma unroll
    for (int m = 0; m < 2; ++m)
#pragma unroll
        for (int i = 0; i < 4; ++i) {
            int R = bm + wid * 32 + m * 16 + ((lane >> 4) << 2) + i;
            float ps = 0.f, pd = 0.f;
#pragma unroll
            for (int nf = 0; nf < 4; ++nf) {
                float v = acc[m][nf][i];
                ps += v * attS[nf];
                pd += v * attD[nf];
                if (R < M)
                    Hb[(size_t)R * IN_FEAT + bn + nf * 16 + (lane & 15)] = f2bf(v);
            }
#pragma unroll
            for (int off = 1; off < 16; off <<= 1) {
                ps += __shfl_xor(ps, off, 64);
                pd += __shfl_xor(pd, off, 64);
            }
            if ((lane & 15) == 0 && R < M) {
                asrc[R * HEADS + h0] = ps;
                adst[R * HEADS + h0] = pd;
            }
        }
}

// ---------------- gather aggregate: one wave per destination node -----------
__global__ __launch_bounds__(256) void aggregate(const unsigned short* __restrict__ Hb,
                                                 const float* __restrict__ asrc,
                                                 const float* __restrict__ adst,
                                                 const int* __restrict__ offsets,
                                                 const int* __restrict__ counts,
                                                 const int* __restrict__ sorted_src,
                                                 const float* __restrict__ bias,
                                                 float* __restrict__ out, int N) {
    int gtid = blockIdx.x * blockDim.x + threadIdx.x;
    int wave = gtid >> 6;
    int lane = threadIdx.x & 63;
    int nwaves = (gridDim.x * blockDim.x) >> 6;
    int head = lane >> 4;
    const float4 bv = *reinterpret_cast<const float4*>(&bias[lane * 4]);
    for (int d = wave; d < N; d += nwaves) {
        const float ad = adst[d * HEADS + head];
        float a = asrc[d * HEADS + head] + ad;
        float w = __expf((a > 0.f) ? a : NEG_SLOPE * a);
        ushort4 ud = *reinterpret_cast<const ushort4*>(&Hb[(size_t)d * IN_FEAT + lane * 4]);
        float4 acc = make_float4(w * bf2f(ud.x), w * bf2f(ud.y),
                                 w * bf2f(ud.z), w * bf2f(ud.w));
        float den = w;
        const int start = offsets[d];
        const int cnt = counts[d];
        int k = 0;
        for (; k + 3 < cnt; k += 4) {
            int s0 = sorted_src[start + k + 0];
            int s1 = sorted_src[start + k + 1];
            int s2 = sorted_src[start + k + 2];
            int s3 = sorted_src[start + k + 3];
            float a0 = asrc[s0 * HEADS + head] + ad;
            float a1 = asrc[s1 * HEADS + head] + ad;
            float a2 = asrc[s2 * HEADS + head] + ad;
            float a3 = asrc[s3 * HEADS + head] + ad;
            ushort4 u0 = *reinterpret_cast<const ushort4*>(&Hb[(size_t)s0 * IN_FEAT + lane * 4]);
            ushort4 u1 = *reinterpret_cast<const ushort4*>(&Hb[(size_t)s1 * IN_FEAT + lane * 4]);
            ushort4 u2 = *reinterpret_cast<const ushort4*>(&Hb[(size_t)s2 * IN_FEAT + lane * 4]);
            ushort4 u3 = *reinterpret_cast<const ushort4*>(&Hb[(size_t)s3 * IN_FEAT + lane * 4]);
            float w0 = __expf((a0 > 0.f) ? a0 : NEG_SLOPE * a0);
            float w1 = __expf((a1 > 0.f) ? a1 : NEG_SLOPE * a1);
            float w2 = __expf((a2 > 0.f) ? a2 : NEG_SLOPE * a2);
            float w3 = __expf((a3 > 0.f) ? a3 : NEG_SLOPE * a3);
            acc.x += w0 * bf2f(u0.x) + w1 * bf2f(u1.x) + w2 * bf2f(u2.x) + w3 * bf2f(u3.x);
            acc.y += w0 * bf2f(u0.y) + w1 * bf2f(u1.y) + w2 * bf2f(u2.y) + w3 * bf2f(u3.y);
            acc.z += w0 * bf2f(u0.z) + w1 * bf2f(u1.z) + w2 * bf2f(u2.z) + w3 * bf2f(u3.z);
            acc.w += w0 * bf2f(u0.w) + w1 * bf2f(u1.w) + w2 * bf2f(u2.w) + w3 * bf2f(u3.w);
            den += w0 + w1 + w2 + w3;
        }
        for (; k < cnt; ++k) {
            int s0 = sorted_src[start + k];
            float a0 = asrc[s0 * HEADS + head] + ad;
            ushort4 u0 = *reinterpret_cast<const ushort4*>(&Hb[(size_t)s0 * IN_FEAT + lane * 4]);
            float w0 = __expf((a0 > 0.f) ? a0 : NEG_SLOPE * a0);
            acc.x += w0 * bf2f(u0.x);
            acc.y += w0 * bf2f(u0.y);
            acc.z += w0 * bf2f(u0.z);
            acc.w += w0 * bf2f(u0.w);
            den += w0;
        }
        const float inv = 1.f / den;
        float4 r;
        r.x = fmaxf(acc.x * inv + bv.x, 0.f);
        r.y = fmaxf(acc.y * inv + bv.y, 0.f);
        r.z = fmaxf(acc.z * inv + bv.z, 0.f);
        r.w = fmaxf(acc.w * inv + bv.w, 0.f);
        *reinterpret_cast<float4*>(&out[(size_t)d * IN_FEAT + lane * 4]) = r;
    }
}

extern "C" void kernel_launch(void* const* d_in, const int* in_sizes, int n_in,
                              void* d_out, int out_size, void* d_ws, size_t ws_size,
                              hipStream_t stream) {
    const float* x       = (const float*)d_in[0];
    const int*   ei      = (const int*)d_in[1];      // harness converts int64 -> int32
    const float* W       = (const float*)d_in[2];
    const float* att_src = (const float*)d_in[3];
    const float* att_dst = (const float*)d_in[4];
    const float* bias    = (const float*)d_in[5];
    float*       out     = (float*)d_out;

    const int N = in_sizes[0] / IN_FEAT;   // 50000
    const int E = in_sizes[1] / 2;         // 800000

    // workspace layout (4B elements unless noted)
    unsigned short* Hb  = (unsigned short*)d_ws;          // N*256 bf16
    float* asrc       = (float*)(Hb + (size_t)N * IN_FEAT);
    float* adst       = asrc + (size_t)N * HEADS;
    int*   counts     = (int*)(adst + (size_t)N * HEADS);
    int*   offsets    = counts + N;
    int*   cursor     = offsets + N;
    int*   sorted_src = cursor + N;                       // E
    int*   gcur       = sorted_src + E;                   // 1
    unsigned short* Wtb = (unsigned short*)(gcur + 4);    // 256*256 bf16

    // CSR build
    zero_counts<<<256, 256, 0, stream>>>(counts, N, gcur);
    hist_kernel<<<2048, 256, 0, stream>>>(ei, counts, E, N);
    scan_atomic<<<(N + 1023) / 1024, 1024, 0, stream>>>(counts, offsets, cursor, gcur, N);
    scatter_kernel<<<2048, 256, 0, stream>>>(ei, cursor, sorted_src, E, N);

    // projection + fused logits
    cvt_w<<<256, 256, 0, stream>>>(W, Wtb);
    {
        int mtiles = (N + 127) / 128;
        gemm_mfma<<<mtiles * 4, 256, 0, stream>>>(x, Wtb, att_src, att_dst,
                                                  Hb, asrc, adst, N);
    }

    // gather aggregation (no atomics)
    aggregate<<<(N * 64 + 255) / 256, 256, 0, stream>>>(Hb, asrc, adst, offsets, counts,
                                                        sorted_src, bias, out, N);
}